// Round 8
// baseline (162.984 us; speedup 1.0000x reference)
//
#include <hip/hip_runtime.h>
#include <math.h>

#define N 1024
#define C 81
#define F 1024
#define K 100
#define NC1 80              // foreground classes
#define SEG 1024            // per-class candidate segment stride
#define HBASE 0x3D00        // hist bucket base (float bits >> 16)
#define HSIZE 1024          // covers score in (0.05, 1]
#define SELCAP 2048

#define SCORE_THRESH 0.05f
#define NMS_THRESH   0.5f
#define BBOX_CLIP    4.135166556742356f   // log(1000/16)
#define IMG_W1       1215.0f
#define IMG_H1       799.0f

typedef unsigned long long u64;
typedef unsigned int u32;

__device__ __forceinline__ float4 decode_box(float4 rb, float4 pb) {
    float w  = pb.z - pb.x + 1.0f, h = pb.w - pb.y + 1.0f;
    float cx = pb.x + 0.5f * w,   cy = pb.y + 0.5f * h;
    float dx = rb.x / 10.0f, dy = rb.y / 10.0f;
    float dw = fminf(rb.z / 5.0f, BBOX_CLIP);
    float dh = fminf(rb.w / 5.0f, BBOX_CLIP);
    float pcx = dx * w + cx, pcy = dy * h + cy;
    float pw = expf(dw) * w, ph = expf(dh) * h;
    float x1 = pcx - 0.5f * pw,        y1 = pcy - 0.5f * ph;
    float x2 = pcx + 0.5f * pw - 1.0f, y2 = pcy + 0.5f * ph - 1.0f;
    x1 = fminf(fmaxf(x1, 0.0f), IMG_W1);
    y1 = fminf(fmaxf(y1, 0.0f), IMG_H1);
    x2 = fminf(fmaxf(x2, 0.0f), IMG_W1);
    y2 = fminf(fmaxf(y2, 0.0f), IMG_H1);
    return make_float4(x1, y1, x2, y2);
}

// ---------------- kernel 1: per-class softmax + compact + sort + NMS -------
// One block per class; self-sufficient from the raw inputs (no intermediate
// arrays). Emits kept candidates into segment c*SEG.. (key/meta/box) + cnt[c].
// No atomics, no flags: the kernel boundary is the sync.
__global__ __launch_bounds__(256) void k_nms(
    const float* __restrict__ logits, const float* __restrict__ boxreg,
    const float* __restrict__ pboxes,
    u64* __restrict__ ckey, u32* __restrict__ cmeta,
    float4* __restrict__ cbox, int* __restrict__ cnt_arr)
{
    const int c = blockIdx.x, tid = threadIdx.x;
    __shared__ u64    skey64[N];      // 8 KB
    __shared__ float4 sbox[N];        // 16 KB (V>64 fallback)
    __shared__ float  sarea[N];       // 4 KB
    __shared__ int    skeep[N];       // 4 KB
    __shared__ int    scnt[256];      // 1 KB

    // per-class softmax: thread owns proposals 4t..4t+3
    float sc4[4];
    #pragma unroll
    for (int i = 0; i < 4; ++i) {
        int n = tid * 4 + i;
        const float4* lp = (const float4*)(logits + (size_t)n * C);
        float last = logits[(size_t)n * C + 80];
        float mx = last;
        float4 v;
        #pragma unroll
        for (int q = 0; q < 20; ++q) {
            v = lp[q];
            mx = fmaxf(mx, fmaxf(fmaxf(v.x, v.y), fmaxf(v.z, v.w)));
        }
        float sum = expf(last - mx);
        #pragma unroll
        for (int q = 0; q < 20; ++q) {
            v = lp[q];
            sum += expf(v.x - mx) + expf(v.y - mx) + expf(v.z - mx) + expf(v.w - mx);
        }
        sc4[i] = expf(logits[(size_t)n * C + (c + 1)] - mx) / sum;
    }

    // order-preserving compaction of valid proposals into skey64
    int f0 = sc4[0] > SCORE_THRESH, f1 = sc4[1] > SCORE_THRESH;
    int f2 = sc4[2] > SCORE_THRESH, f3 = sc4[3] > SCORE_THRESH;
    int mycount = f0 + f1 + f2 + f3;
    scnt[tid] = mycount;
    __syncthreads();
    for (int off = 1; off < 256; off <<= 1) {
        int v = scnt[tid];
        int a = (tid >= off) ? scnt[tid - off] : 0;
        __syncthreads();
        scnt[tid] = v + a;
        __syncthreads();
    }
    int base = scnt[tid] - mycount;
    int V = scnt[255];
    {
        int p0 = tid * 4, pos = base;
        if (f0) skey64[pos++] = ((u64)__float_as_uint(sc4[0]) << 32) | (u32)~(u32)(p0);
        if (f1) skey64[pos++] = ((u64)__float_as_uint(sc4[1]) << 32) | (u32)~(u32)(p0 + 1);
        if (f2) skey64[pos++] = ((u64)__float_as_uint(sc4[2]) << 32) | (u32)~(u32)(p0 + 2);
        if (f3) skey64[pos++] = ((u64)__float_as_uint(sc4[3]) << 32) | (u32)~(u32)(p0 + 3);
    }
    __syncthreads();

    if (V <= 64) {
        // fast path: single-wave shuffle bitonic + shuffle-broadcast NMS
        if (tid < 64) {
            int lane = tid;
            u64 key = (lane < V) ? skey64[lane] : 0ull;
            for (int k = 2; k <= 64; k <<= 1) {
                for (int j = k >> 1; j > 0; j >>= 1) {
                    u64 other = __shfl_xor(key, j);
                    bool takeMax = (((lane & j) == 0) == ((lane & k) == 0));
                    bool gt = key > other;
                    key = (takeMax == gt) ? key : other;
                }
            }
            bool act = key != 0ull;
            float4 mybox = make_float4(0.f, 0.f, 0.f, 0.f);
            float area = 0.0f;
            int myidx = 0;
            if (act) {
                myidx = (int)(~(u32)(key & 0xffffffffu));
                float4 rb = ((const float4*)boxreg)[(size_t)myidx * C + (c + 1)];
                float4 pb = ((const float4*)pboxes)[myidx];
                mybox = decode_box(rb, pb);
                area = (mybox.z - mybox.x + 1.0f) * (mybox.w - mybox.y + 1.0f);
            }
            int kept = act ? 1 : 0;
            for (int i = 0; i + 1 < V; ++i) {
                int   ki  = __shfl(kept, i);
                float bix = __shfl(mybox.x, i), biy = __shfl(mybox.y, i);
                float biz = __shfl(mybox.z, i), biw = __shfl(mybox.w, i);
                float ai  = __shfl(area, i);
                if (ki && lane > i && kept) {
                    float lx = fmaxf(bix, mybox.x), ly = fmaxf(biy, mybox.y);
                    float rx = fminf(biz, mybox.z), ry = fminf(biw, mybox.w);
                    float ww = fmaxf(rx - lx + 1.0f, 0.0f);
                    float hh = fmaxf(ry - ly + 1.0f, 0.0f);
                    float inter = ww * hh;
                    float iou = inter / (ai + area - inter);
                    if (iou > NMS_THRESH) kept = 0;
                }
            }
            u64 ball = __ballot(kept != 0);
            int rank = __popcll(ball & ((1ull << lane) - 1ull));
            if (kept) {
                int slot = c * SEG + rank;
                u32 sb = (u32)(key >> 32);
                ckey[slot]  = ((u64)sb << 32) | (u64)(u32)~(u32)(c * N + lane);
                cmeta[slot] = ((u32)c << 10) | (u32)myidx;
                cbox[slot]  = mybox;
            }
            if (lane == 0) cnt_arr[c] = __popcll(ball);
        }
    } else {
        // fallback: V > 64, LDS bitonic + barriered sequential NMS
        int P = 128;
        while (P < V) P <<= 1;
        for (int i = V + tid; i < P; i += 256) skey64[i] = 0ull;
        __syncthreads();
        for (int k = 2; k <= P; k <<= 1) {
            for (int j = k >> 1; j > 0; j >>= 1) {
                for (int i = tid; i < P; i += 256) {
                    int ixj = i ^ j;
                    if (ixj > i) {
                        u64 a = skey64[i], bb2 = skey64[ixj];
                        bool desc = ((i & k) == 0);
                        if (desc ? (a < bb2) : (a > bb2)) { skey64[i] = bb2; skey64[ixj] = a; }
                    }
                }
                __syncthreads();
            }
        }
        for (int p = tid; p < V; p += 256) {
            int idx = (int)(~(u32)(skey64[p] & 0xffffffffu));
            float4 rb = ((const float4*)boxreg)[(size_t)idx * C + (c + 1)];
            float4 pb = ((const float4*)pboxes)[idx];
            float4 bb2 = decode_box(rb, pb);
            sbox[p]  = bb2;
            sarea[p] = (bb2.z - bb2.x + 1.0f) * (bb2.w - bb2.y + 1.0f);
            skeep[p] = 1;
        }
        __syncthreads();
        for (int i = 0; i < V; ++i) {
            if (skeep[i]) {
                float4 bi = sbox[i];
                float  ai = sarea[i];
                for (int j = i + 1 + tid; j < V; j += 256) {
                    if (skeep[j]) {
                        float4 bj = sbox[j];
                        float lx = fmaxf(bi.x, bj.x), ly = fmaxf(bi.y, bj.y);
                        float rx = fminf(bi.z, bj.z), ry = fminf(bi.w, bj.w);
                        float ww = fmaxf(rx - lx + 1.0f, 0.0f);
                        float hh = fmaxf(ry - ly + 1.0f, 0.0f);
                        float inter = ww * hh;
                        float iou = inter / (ai + sarea[j] - inter);
                        if (iou > NMS_THRESH) skeep[j] = 0;
                    }
                }
            }
            __syncthreads();
        }
        // order-preserving rank via chunked LDS scan (thread owns 4 slots)
        int cn = 0;
        #pragma unroll
        for (int q = 0; q < 4; ++q) {
            int p = tid * 4 + q;
            if (p < V && skeep[p]) cn++;
        }
        scnt[tid] = cn;
        __syncthreads();
        for (int off = 1; off < 256; off <<= 1) {
            int v = scnt[tid];
            int a = (tid >= off) ? scnt[tid - off] : 0;
            __syncthreads();
            scnt[tid] = v + a;
            __syncthreads();
        }
        int rk = scnt[tid] - cn;
        #pragma unroll
        for (int q = 0; q < 4; ++q) {
            int p = tid * 4 + q;
            if (p < V && skeep[p]) {
                int slot = c * SEG + rk;
                u32 sb = (u32)(skey64[p] >> 32);
                int idx = (int)(~(u32)(skey64[p] & 0xffffffffu));
                ckey[slot]  = ((u64)sb << 32) | (u64)(u32)~(u32)(c * N + p);
                cmeta[slot] = ((u32)c << 10) | (u32)idx;
                cbox[slot]  = sbox[p];
                rk++;
            }
        }
        if (tid == 0) cnt_arr[c] = scnt[255];
    }
}

// ---------------- kernel 2: redundant radix-select + per-block gather ------
// 100 blocks; EVERY block runs the full select (keys unique -> identical
// sorted result in all blocks), then block b emits detection rank b.
// Removes the select->gather launch dependency entirely.
__global__ __launch_bounds__(256) void k_selgather(
    const u64* __restrict__ ckey, const u32* __restrict__ cmeta,
    const float4* __restrict__ cbox, const int* __restrict__ cnt_arr,
    const float* __restrict__ feats, float* __restrict__ out)
{
    const int b = blockIdx.x, tid = threadIdx.x;
    __shared__ u64 selk[SELCAP];      // 16 KB
    __shared__ u32 sels[SELCAP];      // 8 KB
    __shared__ int lhist[HSIZE];      // 4 KB
    __shared__ int scnt[256];         // 1 KB
    __shared__ int scounts[NC1];
    __shared__ int sb_bstar, scount;

    for (int i = tid; i < HSIZE; i += 256) lhist[i] = 0;
    if (tid < NC1) scounts[tid] = cnt_arr[tid];
    if (tid == 0) { sb_bstar = 0; scount = 0; }
    __syncthreads();

    // pass 1: histogram of all candidate score-buckets
    int M = 0;
    for (int c = 0; c < NC1; ++c) {
        int cc = scounts[c];
        M += cc;
        for (int i = tid; i < cc; i += 256) {
            u64 kk = ckey[c * SEG + i];
            atomicAdd(&lhist[(int)((kk >> 48) & 0xFFFF) - HBASE], 1);
        }
    }
    __syncthreads();

    // suffix scan over 1024 buckets -> bucket containing K-th largest
    int lo4 = tid * 4;
    int h0 = lhist[lo4], h1 = lhist[lo4 + 1], h2 = lhist[lo4 + 2], h3 = lhist[lo4 + 3];
    int lsum = h0 + h1 + h2 + h3;
    scnt[tid] = lsum;
    __syncthreads();
    for (int off = 1; off < 256; off <<= 1) {
        int v = scnt[tid];
        int a = (tid + off < 256) ? scnt[tid + off] : 0;
        __syncthreads();
        scnt[tid] = v + a;
        __syncthreads();
    }
    int basek = scnt[tid] - lsum;
    if (basek < K && basek + lsum >= K) {
        int hh[4] = {h0, h1, h2, h3};
        int run = basek;
        for (int q = 3; q >= 0; --q) {
            if (run < K && run + hh[q] >= K) { sb_bstar = lo4 + q; break; }
            run += hh[q];
        }
    }
    __syncthreads();
    int bstar = sb_bstar;

    // pass 2: compact qualifying keys into LDS
    for (int c = 0; c < NC1; ++c) {
        int cc = scounts[c];
        for (int i = tid; i < cc; i += 256) {
            int slot = c * SEG + i;
            u64 kk = ckey[slot];
            if ((int)((kk >> 48) & 0xFFFF) - HBASE >= bstar) {
                int pos = atomicAdd(&scount, 1);
                if (pos < SELCAP) { selk[pos] = kk; sels[pos] = (u32)slot; }
            }
        }
    }
    __syncthreads();
    int cnt = scount;

    u64 key = 0ull;
    u32 slot = 0;
    if (cnt <= SELCAP) {
        int P = 128;
        while (P < cnt) P <<= 1;
        for (int i = cnt + tid; i < P; i += 256) selk[i] = 0ull;
        __syncthreads();
        for (int k = 2; k <= P; k <<= 1) {
            for (int j = k >> 1; j > 0; j >>= 1) {
                for (int i = tid; i < P; i += 256) {
                    int ixj = i ^ j;
                    if (ixj > i) {
                        u64 a = selk[i], bb2 = selk[ixj];
                        bool desc = ((i & k) == 0);
                        if (desc ? (a < bb2) : (a > bb2)) {
                            selk[i] = bb2; selk[ixj] = a;
                            u32 tmp = sels[i]; sels[i] = sels[ixj]; sels[ixj] = tmp;
                        }
                    }
                }
                __syncthreads();
            }
        }
        key = selk[b]; slot = sels[b];
    } else {
        // exact fallback (tie flood): iterative "max key strictly below last"
        // until reaching rank b. Deterministic (keys unique).
        __shared__ u64 wres; __shared__ u32 wslot;
        u64 last = ~0ull;
        for (int r = 0; r <= b; ++r) {
            u64 best = 0ull; u32 bslot = 0;
            for (int c = 0; c < NC1; ++c) {
                int cc = scounts[c];
                for (int i = tid; i < cc; i += 256) {
                    int sl = c * SEG + i;
                    u64 kk = ckey[sl];
                    if (kk < last && kk > best) { best = kk; bslot = (u32)sl; }
                }
            }
            for (int off = 32; off; off >>= 1) {
                u64 ok2 = __shfl_down(best, off);
                u32 os = __shfl_down(bslot, off);
                if (ok2 > best) { best = ok2; bslot = os; }
            }
            if (tid == 0) { wres = best; wslot = bslot; }
            __syncthreads();
            // block reduce across 4 waves via LDS
            if (tid == 64 || tid == 128 || tid == 192) {
                // serialized by barrier below; use atomic-free max via CAS loop
            }
            __syncthreads();
            // simple: wave 0 result only is wrong; do proper 4-wave reduce:
            if ((tid & 63) == 0) {
                selk[tid >> 6] = best; sels[tid >> 6] = bslot;
            }
            __syncthreads();
            if (tid == 0) {
                u64 bk = selk[0]; u32 bs = sels[0];
                for (int w = 1; w < 4; ++w)
                    if (selk[w] > bk) { bk = selk[w]; bs = sels[w]; }
                wres = bk; wslot = bs;
            }
            __syncthreads();
            last = wres;
            if (r == b) { key = wres; slot = wslot; }
            __syncthreads();
        }
    }

    // gather: block b emits detection rank b
    bool okk = key != 0ull;
    float s = okk ? __uint_as_float((u32)(key >> 32)) : 0.0f;
    float4 bb = make_float4(0.f, 0.f, 0.f, 0.f);
    int label = 0, orig = 0;
    if (okk) {
        u32 meta = cmeta[slot];
        orig  = (int)(meta & 1023u);
        label = (int)(meta >> 10) + 1;
        bb    = cbox[slot];
    }
    if (tid == 0) {
        out[b * 4 + 0] = bb.x; out[b * 4 + 1] = bb.y;
        out[b * 4 + 2] = bb.z; out[b * 4 + 3] = bb.w;
        out[K * 4 + b] = s;
        out[K * 4 + K + K * F + b] = (float)label;
    }
    const float4* src = (const float4*)(feats + (size_t)orig * F);
    float4* dst = (float4*)(out + K * 4 + K + (size_t)b * F);
    float4 z = make_float4(0.f, 0.f, 0.f, 0.f);
    dst[tid] = okk ? src[tid] : z;           // 256 threads x float4 == F
}

// ---------------------------------------------------------------------------
extern "C" void kernel_launch(void* const* d_in, const int* in_sizes, int n_in,
                              void* d_out, int out_size, void* d_ws, size_t ws_size,
                              hipStream_t stream)
{
    const float* logits = (const float*)d_in[0];   // [N,C]
    const float* boxreg = (const float*)d_in[1];   // [N,C*4]
    const float* pboxes = (const float*)d_in[2];   // [N,4]
    const float* feats  = (const float*)d_in[3];   // [N,F]
    float* out = (float*)d_out;

    char* ws = (char*)d_ws;
    size_t off = 0;
    auto alloc = [&](size_t bytes) {
        size_t cur = off;
        off = (off + bytes + 255) & ~(size_t)255;
        return cur;
    };
    u64*    ckey    = (u64*)   (ws + alloc(sizeof(u64)    * NC1 * SEG));
    u32*    cmeta   = (u32*)   (ws + alloc(sizeof(u32)    * NC1 * SEG));
    float4* cbox    = (float4*)(ws + alloc(sizeof(float4) * NC1 * SEG));
    int*    cnt_arr = (int*)   (ws + alloc(sizeof(int)    * NC1));

    hipLaunchKernelGGL(k_nms, dim3(NC1), dim3(256), 0, stream,
                       logits, boxreg, pboxes, ckey, cmeta, cbox, cnt_arr);
    hipLaunchKernelGGL(k_selgather, dim3(K), dim3(256), 0, stream,
                       ckey, cmeta, cbox, cnt_arr, feats, out);
}

// Round 9
// 140.801 us; speedup vs baseline: 1.1576x; 1.1576x over previous
//
#include <hip/hip_runtime.h>
#include <math.h>

#define N 1024
#define C 81
#define F 1024
#define K 100
#define NC1 80              // foreground classes
#define SEG 1024            // per-class candidate segment stride
#define HBASE 0x3D00        // hist bucket base (float bits >> 16)
#define HSIZE 1024          // covers score in (0.05, 1]
#define SELCAP 2048
#define REGC 16             // register key cache: covers M <= 4096

#define SCORE_THRESH 0.05f
#define NMS_THRESH   0.5f
#define BBOX_CLIP    4.135166556742356f   // log(1000/16)
#define IMG_W1       1215.0f
#define IMG_H1       799.0f

typedef unsigned long long u64;
typedef unsigned int u32;

__device__ __forceinline__ float4 decode_box(float4 rb, float4 pb) {
    float w  = pb.z - pb.x + 1.0f, h = pb.w - pb.y + 1.0f;
    float cx = pb.x + 0.5f * w,   cy = pb.y + 0.5f * h;
    float dx = rb.x / 10.0f, dy = rb.y / 10.0f;
    float dw = fminf(rb.z / 5.0f, BBOX_CLIP);
    float dh = fminf(rb.w / 5.0f, BBOX_CLIP);
    float pcx = dx * w + cx, pcy = dy * h + cy;
    float pw = expf(dw) * w, ph = expf(dh) * h;
    float x1 = pcx - 0.5f * pw,        y1 = pcy - 0.5f * ph;
    float x2 = pcx + 0.5f * pw - 1.0f, y2 = pcy + 0.5f * ph - 1.0f;
    x1 = fminf(fmaxf(x1, 0.0f), IMG_W1);
    y1 = fminf(fmaxf(y1, 0.0f), IMG_H1);
    x2 = fminf(fmaxf(x2, 0.0f), IMG_W1);
    y2 = fminf(fmaxf(y2, 0.0f), IMG_H1);
    return make_float4(x1, y1, x2, y2);
}

// ---------------- kernel 1: per-class softmax + compact + sort + NMS -------
// One block per class; self-sufficient from raw inputs. Emits kept candidates
// into segment c*SEG (key/meta/box) + cnt[c]. No atomics; boundary = sync.
__global__ __launch_bounds__(256) void k_nms(
    const float* __restrict__ logits, const float* __restrict__ boxreg,
    const float* __restrict__ pboxes,
    u64* __restrict__ ckey, u32* __restrict__ cmeta,
    float4* __restrict__ cbox, int* __restrict__ cnt_arr)
{
    const int c = blockIdx.x, tid = threadIdx.x;
    __shared__ u64    skey64[N];      // 8 KB
    __shared__ float4 sbox[N];        // 16 KB (V>64 fallback)
    __shared__ float  sarea[N];       // 4 KB
    __shared__ int    skeep[N];       // 4 KB
    __shared__ int    scnt[256];      // 1 KB

    // per-class softmax: thread owns proposals 4t..4t+3
    float sc4[4];
    #pragma unroll
    for (int i = 0; i < 4; ++i) {
        int n = tid * 4 + i;
        const float4* lp = (const float4*)(logits + (size_t)n * C);
        float last = logits[(size_t)n * C + 80];
        float mx = last;
        float4 v;
        #pragma unroll
        for (int q = 0; q < 20; ++q) {
            v = lp[q];
            mx = fmaxf(mx, fmaxf(fmaxf(v.x, v.y), fmaxf(v.z, v.w)));
        }
        float sum = expf(last - mx);
        #pragma unroll
        for (int q = 0; q < 20; ++q) {
            v = lp[q];
            sum += expf(v.x - mx) + expf(v.y - mx) + expf(v.z - mx) + expf(v.w - mx);
        }
        sc4[i] = expf(logits[(size_t)n * C + (c + 1)] - mx) / sum;
    }

    // order-preserving compaction of valid proposals into skey64
    int f0 = sc4[0] > SCORE_THRESH, f1 = sc4[1] > SCORE_THRESH;
    int f2 = sc4[2] > SCORE_THRESH, f3 = sc4[3] > SCORE_THRESH;
    int mycount = f0 + f1 + f2 + f3;
    scnt[tid] = mycount;
    __syncthreads();
    for (int off = 1; off < 256; off <<= 1) {
        int v = scnt[tid];
        int a = (tid >= off) ? scnt[tid - off] : 0;
        __syncthreads();
        scnt[tid] = v + a;
        __syncthreads();
    }
    int base = scnt[tid] - mycount;
    int V = scnt[255];
    {
        int p0 = tid * 4, pos = base;
        if (f0) skey64[pos++] = ((u64)__float_as_uint(sc4[0]) << 32) | (u32)~(u32)(p0);
        if (f1) skey64[pos++] = ((u64)__float_as_uint(sc4[1]) << 32) | (u32)~(u32)(p0 + 1);
        if (f2) skey64[pos++] = ((u64)__float_as_uint(sc4[2]) << 32) | (u32)~(u32)(p0 + 2);
        if (f3) skey64[pos++] = ((u64)__float_as_uint(sc4[3]) << 32) | (u32)~(u32)(p0 + 3);
    }
    __syncthreads();

    if (V <= 64) {
        // fast path: single-wave shuffle bitonic + shuffle-broadcast NMS
        if (tid < 64) {
            int lane = tid;
            u64 key = (lane < V) ? skey64[lane] : 0ull;
            for (int k = 2; k <= 64; k <<= 1) {
                for (int j = k >> 1; j > 0; j >>= 1) {
                    u64 other = __shfl_xor(key, j);
                    bool takeMax = (((lane & j) == 0) == ((lane & k) == 0));
                    bool gt = key > other;
                    key = (takeMax == gt) ? key : other;
                }
            }
            bool act = key != 0ull;
            float4 mybox = make_float4(0.f, 0.f, 0.f, 0.f);
            float area = 0.0f;
            int myidx = 0;
            if (act) {
                myidx = (int)(~(u32)(key & 0xffffffffu));
                float4 rb = ((const float4*)boxreg)[(size_t)myidx * C + (c + 1)];
                float4 pb = ((const float4*)pboxes)[myidx];
                mybox = decode_box(rb, pb);
                area = (mybox.z - mybox.x + 1.0f) * (mybox.w - mybox.y + 1.0f);
            }
            int kept = act ? 1 : 0;
            for (int i = 0; i + 1 < V; ++i) {
                int   ki  = __shfl(kept, i);
                float bix = __shfl(mybox.x, i), biy = __shfl(mybox.y, i);
                float biz = __shfl(mybox.z, i), biw = __shfl(mybox.w, i);
                float ai  = __shfl(area, i);
                if (ki && lane > i && kept) {
                    float lx = fmaxf(bix, mybox.x), ly = fmaxf(biy, mybox.y);
                    float rx = fminf(biz, mybox.z), ry = fminf(biw, mybox.w);
                    float ww = fmaxf(rx - lx + 1.0f, 0.0f);
                    float hh = fmaxf(ry - ly + 1.0f, 0.0f);
                    float inter = ww * hh;
                    float iou = inter / (ai + area - inter);
                    if (iou > NMS_THRESH) kept = 0;
                }
            }
            u64 ball = __ballot(kept != 0);
            int rank = __popcll(ball & ((1ull << lane) - 1ull));
            if (kept) {
                int slot = c * SEG + rank;
                u32 sb = (u32)(key >> 32);
                ckey[slot]  = ((u64)sb << 32) | (u64)(u32)~(u32)(c * N + lane);
                cmeta[slot] = ((u32)c << 10) | (u32)myidx;
                cbox[slot]  = mybox;
            }
            if (lane == 0) cnt_arr[c] = __popcll(ball);
        }
    } else {
        // fallback: V > 64, LDS bitonic + barriered sequential NMS
        int P = 128;
        while (P < V) P <<= 1;
        for (int i = V + tid; i < P; i += 256) skey64[i] = 0ull;
        __syncthreads();
        for (int k = 2; k <= P; k <<= 1) {
            for (int j = k >> 1; j > 0; j >>= 1) {
                for (int i = tid; i < P; i += 256) {
                    int ixj = i ^ j;
                    if (ixj > i) {
                        u64 a = skey64[i], bb2 = skey64[ixj];
                        bool desc = ((i & k) == 0);
                        if (desc ? (a < bb2) : (a > bb2)) { skey64[i] = bb2; skey64[ixj] = a; }
                    }
                }
                __syncthreads();
            }
        }
        for (int p = tid; p < V; p += 256) {
            int idx = (int)(~(u32)(skey64[p] & 0xffffffffu));
            float4 rb = ((const float4*)boxreg)[(size_t)idx * C + (c + 1)];
            float4 pb = ((const float4*)pboxes)[idx];
            float4 bb2 = decode_box(rb, pb);
            sbox[p]  = bb2;
            sarea[p] = (bb2.z - bb2.x + 1.0f) * (bb2.w - bb2.y + 1.0f);
            skeep[p] = 1;
        }
        __syncthreads();
        for (int i = 0; i < V; ++i) {
            if (skeep[i]) {
                float4 bi = sbox[i];
                float  ai = sarea[i];
                for (int j = i + 1 + tid; j < V; j += 256) {
                    if (skeep[j]) {
                        float4 bj = sbox[j];
                        float lx = fmaxf(bi.x, bj.x), ly = fmaxf(bi.y, bj.y);
                        float rx = fminf(bi.z, bj.z), ry = fminf(bi.w, bj.w);
                        float ww = fmaxf(rx - lx + 1.0f, 0.0f);
                        float hh = fmaxf(ry - ly + 1.0f, 0.0f);
                        float inter = ww * hh;
                        float iou = inter / (ai + sarea[j] - inter);
                        if (iou > NMS_THRESH) skeep[j] = 0;
                    }
                }
            }
            __syncthreads();
        }
        int cn = 0;
        #pragma unroll
        for (int q = 0; q < 4; ++q) {
            int p = tid * 4 + q;
            if (p < V && skeep[p]) cn++;
        }
        scnt[tid] = cn;
        __syncthreads();
        for (int off = 1; off < 256; off <<= 1) {
            int v = scnt[tid];
            int a = (tid >= off) ? scnt[tid - off] : 0;
            __syncthreads();
            scnt[tid] = v + a;
            __syncthreads();
        }
        int rk = scnt[tid] - cn;
        #pragma unroll
        for (int q = 0; q < 4; ++q) {
            int p = tid * 4 + q;
            if (p < V && skeep[p]) {
                int slot = c * SEG + rk;
                u32 sb = (u32)(skey64[p] >> 32);
                int idx = (int)(~(u32)(skey64[p] & 0xffffffffu));
                ckey[slot]  = ((u64)sb << 32) | (u64)(u32)~(u32)(c * N + p);
                cmeta[slot] = ((u32)c << 10) | (u32)idx;
                cbox[slot]  = sbox[p];
                rk++;
            }
        }
        if (tid == 0) cnt_arr[c] = scnt[255];
    }
}

// ---------------- kernel 2: redundant radix-select + per-block gather ------
// 100 blocks; EVERY block runs the full select (keys unique -> identical
// result in all blocks; redundancy is free across parallel blocks), then
// block b emits detection rank b. Select touches global memory ONCE via a
// fully-unrolled 16-deep register load burst (ILP hides L2 latency).
__global__ __launch_bounds__(256) void k_selgather(
    const u64* __restrict__ ckey, const u32* __restrict__ cmeta,
    const float4* __restrict__ cbox, const int* __restrict__ cnt_arr,
    const float* __restrict__ feats, float* __restrict__ out)
{
    const int b = blockIdx.x, tid = threadIdx.x;
    __shared__ u64 selk[SELCAP];      // 16 KB
    __shared__ u32 sels[SELCAP];      // 8 KB
    __shared__ int lhist[HSIZE];      // 4 KB
    __shared__ int scnt[256];         // 1 KB
    __shared__ int pref[NC1 + 1];
    __shared__ int sb_bstar, scount;

    for (int i = tid; i < HSIZE; i += 256) lhist[i] = 0;
    if (tid == 0) { sb_bstar = 0; scount = 0; }
    // prefix over class counts (wave 0, serial-in-lane0 is fine: 80 adds)
    if (tid == 0) {
        int s = 0;
        for (int c2 = 0; c2 < NC1; ++c2) { pref[c2] = s; s += cnt_arr[c2]; }
        pref[NC1] = s;
    }
    __syncthreads();
    const int M = pref[NC1];

    u64 key = 0ull;
    u32 slot = 0;

    if (M <= REGC * 256) {
        // ---- phase 1: flat slot computation + burst load into registers ----
        int slots[REGC];
        #pragma unroll
        for (int q = 0; q < REGC; ++q) {
            int i = tid + q * 256;
            int sl = -1;
            if (i < M) {
                int lo = 0, hi = NC1 - 1;
                while (lo < hi) { int mid = (lo + hi + 1) >> 1; if (pref[mid] <= i) lo = mid; else hi = mid - 1; }
                sl = lo * SEG + (i - pref[lo]);
            }
            slots[q] = sl;
        }
        u64 rk[REGC];
        #pragma unroll
        for (int q = 0; q < REGC; ++q)
            rk[q] = (slots[q] >= 0) ? ckey[slots[q]] : 0ull;   // 16 loads in flight

        // ---- phase 2: LDS histogram from registers ----
        #pragma unroll
        for (int q = 0; q < REGC; ++q)
            if (slots[q] >= 0)
                atomicAdd(&lhist[(int)((rk[q] >> 48) & 0xFFFF) - HBASE], 1);
        __syncthreads();

        // suffix scan over 1024 buckets -> bucket containing K-th largest
        int lo4 = tid * 4;
        int h0 = lhist[lo4], h1 = lhist[lo4 + 1], h2 = lhist[lo4 + 2], h3 = lhist[lo4 + 3];
        int lsum = h0 + h1 + h2 + h3;
        scnt[tid] = lsum;
        __syncthreads();
        for (int off = 1; off < 256; off <<= 1) {
            int v = scnt[tid];
            int a = (tid + off < 256) ? scnt[tid + off] : 0;
            __syncthreads();
            scnt[tid] = v + a;
            __syncthreads();
        }
        int basek = scnt[tid] - lsum;
        if (basek < K && basek + lsum >= K) {
            int hh[4] = {h0, h1, h2, h3};
            int run = basek;
            for (int q = 3; q >= 0; --q) {
                if (run < K && run + hh[q] >= K) { sb_bstar = lo4 + q; break; }
                run += hh[q];
            }
        }
        __syncthreads();
        int bstar = sb_bstar;

        // ---- phase 3: compact qualifying keys from registers into LDS ----
        #pragma unroll
        for (int q = 0; q < REGC; ++q) {
            if (slots[q] >= 0 && (int)((rk[q] >> 48) & 0xFFFF) - HBASE >= bstar) {
                int pos = atomicAdd(&scount, 1);
                if (pos < SELCAP) { selk[pos] = rk[q]; sels[pos] = (u32)slots[q]; }
            }
        }
        __syncthreads();
        int cnt = scount;                      // in [K, K + bucket pop)

        // ---- phase 4: bitonic sort, take rank b ----
        int P = 128;
        while (P < cnt && P < SELCAP) P <<= 1;
        for (int i = cnt + tid; i < P; i += 256) selk[i] = 0ull;
        __syncthreads();
        for (int k = 2; k <= P; k <<= 1) {
            for (int j = k >> 1; j > 0; j >>= 1) {
                for (int i = tid; i < P; i += 256) {
                    int ixj = i ^ j;
                    if (ixj > i) {
                        u64 a = selk[i], bb2 = selk[ixj];
                        bool desc = ((i & k) == 0);
                        if (desc ? (a < bb2) : (a > bb2)) {
                            selk[i] = bb2; selk[ixj] = a;
                            u32 tmp = sels[i]; sels[i] = sels[ixj]; sels[ixj] = tmp;
                        }
                    }
                }
                __syncthreads();
            }
        }
        if (cnt <= SELCAP) { key = selk[b]; slot = sels[b]; }
        else {
            // overflow (pathological tie flood): exact rank-b via iterative max
            u64 last = ~0ull;
            for (int r = 0; r <= b; ++r) {
                u64 best = 0ull; u32 bslot = 0;
                #pragma unroll
                for (int q = 0; q < REGC; ++q) {
                    if (slots[q] >= 0 && rk[q] < last && rk[q] > best) { best = rk[q]; bslot = (u32)slots[q]; }
                }
                for (int off = 32; off; off >>= 1) {
                    u64 ok2 = __shfl_down(best, off);
                    u32 os = __shfl_down(bslot, off);
                    if (ok2 > best) { best = ok2; bslot = os; }
                }
                if ((tid & 63) == 0) { selk[tid >> 6] = best; sels[tid >> 6] = bslot; }
                __syncthreads();
                if (tid == 0) {
                    u64 bk = selk[0]; u32 bs = sels[0];
                    for (int w = 1; w < 4; ++w)
                        if (selk[w] > bk) { bk = selk[w]; bs = sels[w]; }
                    selk[4] = bk; sels[4] = bs;
                }
                __syncthreads();
                last = selk[4];
                if (r == b) { key = selk[4]; slot = sels[4]; }
                __syncthreads();
            }
        }
    } else {
        // ---- streaming fallback for M > 4096 (rare): two global passes ----
        for (int i = tid; i < M; i += 256) {
            int lo = 0, hi = NC1 - 1;
            while (lo < hi) { int mid = (lo + hi + 1) >> 1; if (pref[mid] <= i) lo = mid; else hi = mid - 1; }
            u64 kk = ckey[lo * SEG + (i - pref[lo])];
            atomicAdd(&lhist[(int)((kk >> 48) & 0xFFFF) - HBASE], 1);
        }
        __syncthreads();
        int lo4 = tid * 4;
        int h0 = lhist[lo4], h1 = lhist[lo4 + 1], h2 = lhist[lo4 + 2], h3 = lhist[lo4 + 3];
        int lsum = h0 + h1 + h2 + h3;
        scnt[tid] = lsum;
        __syncthreads();
        for (int off = 1; off < 256; off <<= 1) {
            int v = scnt[tid];
            int a = (tid + off < 256) ? scnt[tid + off] : 0;
            __syncthreads();
            scnt[tid] = v + a;
            __syncthreads();
        }
        int basek = scnt[tid] - lsum;
        if (basek < K && basek + lsum >= K) {
            int hh[4] = {h0, h1, h2, h3};
            int run = basek;
            for (int q = 3; q >= 0; --q) {
                if (run < K && run + hh[q] >= K) { sb_bstar = lo4 + q; break; }
                run += hh[q];
            }
        }
        __syncthreads();
        int bstar = sb_bstar;
        for (int i = tid; i < M; i += 256) {
            int lo = 0, hi = NC1 - 1;
            while (lo < hi) { int mid = (lo + hi + 1) >> 1; if (pref[mid] <= i) lo = mid; else hi = mid - 1; }
            int sl = lo * SEG + (i - pref[lo]);
            u64 kk = ckey[sl];
            if ((int)((kk >> 48) & 0xFFFF) - HBASE >= bstar) {
                int pos = atomicAdd(&scount, 1);
                if (pos < SELCAP) { selk[pos] = kk; sels[pos] = (u32)sl; }
            }
        }
        __syncthreads();
        int cnt = scount;
        int P = 128;
        while (P < cnt && P < SELCAP) P <<= 1;
        if (cnt > SELCAP) P = SELCAP;     // truncated but deterministic; ties beyond cap
        for (int i = cnt + tid; i < P; i += 256) selk[i] = 0ull;
        __syncthreads();
        for (int k = 2; k <= P; k <<= 1) {
            for (int j = k >> 1; j > 0; j >>= 1) {
                for (int i = tid; i < P; i += 256) {
                    int ixj = i ^ j;
                    if (ixj > i) {
                        u64 a = selk[i], bb2 = selk[ixj];
                        bool desc = ((i & k) == 0);
                        if (desc ? (a < bb2) : (a > bb2)) {
                            selk[i] = bb2; selk[ixj] = a;
                            u32 tmp = sels[i]; sels[i] = sels[ixj]; sels[ixj] = tmp;
                        }
                    }
                }
                __syncthreads();
            }
        }
        key = selk[b]; slot = sels[b];
    }

    // ---- gather: block b emits detection rank b ----
    bool okk = key != 0ull;
    float s = okk ? __uint_as_float((u32)(key >> 32)) : 0.0f;
    float4 bb = make_float4(0.f, 0.f, 0.f, 0.f);
    int label = 0, orig = 0;
    if (okk) {
        u32 meta = cmeta[slot];
        orig  = (int)(meta & 1023u);
        label = (int)(meta >> 10) + 1;
        bb    = cbox[slot];
    }
    if (tid == 0) {
        out[b * 4 + 0] = bb.x; out[b * 4 + 1] = bb.y;
        out[b * 4 + 2] = bb.z; out[b * 4 + 3] = bb.w;
        out[K * 4 + b] = s;
        out[K * 4 + K + K * F + b] = (float)label;
    }
    const float4* src = (const float4*)(feats + (size_t)orig * F);
    float4* dst = (float4*)(out + K * 4 + K + (size_t)b * F);
    float4 z = make_float4(0.f, 0.f, 0.f, 0.f);
    dst[tid] = okk ? src[tid] : z;           // 256 threads x float4 == F
}

// ---------------------------------------------------------------------------
extern "C" void kernel_launch(void* const* d_in, const int* in_sizes, int n_in,
                              void* d_out, int out_size, void* d_ws, size_t ws_size,
                              hipStream_t stream)
{
    const float* logits = (const float*)d_in[0];   // [N,C]
    const float* boxreg = (const float*)d_in[1];   // [N,C*4]
    const float* pboxes = (const float*)d_in[2];   // [N,4]
    const float* feats  = (const float*)d_in[3];   // [N,F]
    float* out = (float*)d_out;

    char* ws = (char*)d_ws;
    size_t off = 0;
    auto alloc = [&](size_t bytes) {
        size_t cur = off;
        off = (off + bytes + 255) & ~(size_t)255;
        return cur;
    };
    u64*    ckey    = (u64*)   (ws + alloc(sizeof(u64)    * NC1 * SEG));
    u32*    cmeta   = (u32*)   (ws + alloc(sizeof(u32)    * NC1 * SEG));
    float4* cbox    = (float4*)(ws + alloc(sizeof(float4) * NC1 * SEG));
    int*    cnt_arr = (int*)   (ws + alloc(sizeof(int)    * NC1));

    hipLaunchKernelGGL(k_nms, dim3(NC1), dim3(256), 0, stream,
                       logits, boxreg, pboxes, ckey, cmeta, cbox, cnt_arr);
    hipLaunchKernelGGL(k_selgather, dim3(K), dim3(256), 0, stream,
                       ckey, cmeta, cbox, cnt_arr, feats, out);
}